// Round 1
// baseline (137.348 us; speedup 1.0000x reference)
//
#include <hip/hip_runtime.h>

#define NB 4
#define NE 16
#define NH 512
#define NW 512
#define NHW (NH*NW)
#define NINST 32
#define NS_ (NINST+1)          // 33 segments per batch
#define SP 17                  // padded LDS stride (17 coprime with 32 banks)
#define DELTA_VAR 0.5f
#define DELTA_DIST 1.5f
#define ALPHA 1.0f
#define BETA 1.0f
#define GAMMA 0.001f

#define GRID_BIG 1024
#define BLK 256
#define BPB (GRID_BIG/NB)      // 256 blocks per batch

// per-shard table: sums[NB*NS_*NE] then counts[NB*NS_]
#define SUMSZ (NB*NS_*NE)      // 2112
#define CNTSZ (NB*NS_)         // 132
#define TABLE (SUMSZ + CNTSZ)  // 2244
// final tbl layout (floats):
//  [0,2112)      final sums
//  [2112,2244)   final counts
//  [2244,4356)   means
//  [4356,4360)   var partial per batch
//  [4360,4364)   dist_loss per batch
//  [4364,4368)   reg_loss per batch
//  [4368,4372)   n_safe per batch
#define T_CNT 2112
#define T_MEAN 2244
#define T_VARP 4356
#define T_DIST 4360
#define T_REG 4364
#define T_NS 4368
#define T_TOTAL 4372

__device__ __forceinline__ float wave_sum(float v) {
    #pragma unroll
    for (int o = 32; o > 0; o >>= 1) v += __shfl_down(v, o, 64);
    return v;
}

__global__ __launch_bounds__(BLK) void k_hist(const float* __restrict__ emb,
        const int* __restrict__ lab, float* __restrict__ shards, int nshard) {
    __shared__ float lsum[NS_*SP];
    __shared__ float lcnt[NS_];
    const int t = threadIdx.x;
    const int b = blockIdx.x / BPB;
    const int blk = blockIdx.x % BPB;
    for (int i = t; i < NS_*SP; i += BLK) lsum[i] = 0.f;
    if (t < NS_) lcnt[t] = 0.f;
    __syncthreads();
    const float* ebase = emb + (size_t)b*(NE*NHW);
    const int* lbase = lab + b*NHW;
    for (int q = blk*BLK + t; q < NHW/4; q += BPB*BLK) {
        const int p = q*4;
        const int4 l4 = *(const int4*)(lbase + p);
        const int o0 = l4.x*SP, o1 = l4.y*SP, o2 = l4.z*SP, o3 = l4.w*SP;
        atomicAdd(&lcnt[l4.x], 1.f);
        atomicAdd(&lcnt[l4.y], 1.f);
        atomicAdd(&lcnt[l4.z], 1.f);
        atomicAdd(&lcnt[l4.w], 1.f);
        #pragma unroll
        for (int e = 0; e < NE; e++) {
            const float4 v = *(const float4*)(ebase + (size_t)e*NHW + p);
            atomicAdd(&lsum[o0+e], v.x);
            atomicAdd(&lsum[o1+e], v.y);
            atomicAdd(&lsum[o2+e], v.z);
            atomicAdd(&lsum[o3+e], v.w);
        }
    }
    __syncthreads();
    float* sh = shards + (size_t)(blk % nshard)*TABLE;
    for (int i = t; i < NS_*NE; i += BLK) {
        const int s = i/NE, e = i%NE;
        const float v = lsum[s*SP+e];
        atomicAdd(&sh[(b*NS_+s)*NE + e], v);
    }
    if (t < NS_) atomicAdd(&sh[SUMSZ + b*NS_ + t], lcnt[t]);
}

__global__ void k_reduce(const float* __restrict__ shards, float* __restrict__ tbl, int nshard) {
    const int i = blockIdx.x*blockDim.x + threadIdx.x;
    if (i < TABLE) {
        float s = 0.f;
        for (int sh = 0; sh < nshard; sh++) s += shards[(size_t)sh*TABLE + i];
        tbl[i] = s;
    }
}

__global__ void k_stats(float* __restrict__ tbl) {
    const int b = blockIdx.x;
    const int lane = threadIdx.x;
    __shared__ float lmean[NINST*SP];
    __shared__ int lpres[NINST];
    const float* cnt = tbl + T_CNT + b*NS_;
    for (int idx = lane; idx < NS_*NE; idx += 64) {
        const int s = idx/NE, e = idx%NE;
        const float m = tbl[(b*NS_+s)*NE+e] / fmaxf(cnt[s], 1.f);
        tbl[T_MEAN + (b*NS_+s)*NE+e] = m;
        if (s >= 1) lmean[(s-1)*SP+e] = m;
    }
    if (lane < NINST) lpres[lane] = (cnt[1+lane] > 0.f) ? 1 : 0;
    __syncthreads();
    const int n = __popcll(__ballot(lane < NINST && lpres[lane]));
    float dsum = 0.f;
    for (int idx = lane; idx < NINST*NINST; idx += 64) {
        const int i = idx >> 5, j = idx & 31;
        if (i < j && lpres[i] && lpres[j]) {
            float d2 = 0.f;
            #pragma unroll
            for (int e = 0; e < NE; e++) {
                const float df = lmean[i*SP+e] - lmean[j*SP+e];
                d2 += df*df;
            }
            dsum += fmaxf(2.f*DELTA_DIST - sqrtf(d2), 0.f);
        }
    }
    dsum = wave_sum(dsum);
    float rsum = 0.f;
    if (lane < NINST && lpres[lane]) {
        float s2 = 0.f;
        #pragma unroll
        for (int e = 0; e < NE; e++) { const float m = lmean[lane*SP+e]; s2 += m*m; }
        rsum = sqrtf(s2);
    }
    rsum = wave_sum(rsum);
    if (lane == 0) {
        const float nf = (float)n;
        const float nsafe = fmaxf(nf, 1.f);
        tbl[T_DIST+b] = (n > 1) ? dsum / fmaxf(nf*(nf-1.f)*0.5f, 1.f) : 0.f;
        tbl[T_REG+b] = rsum / nsafe;
        tbl[T_NS+b] = nsafe;
    }
}

__global__ __launch_bounds__(BLK) void k_var(const float* __restrict__ emb,
        const int* __restrict__ lab, float* __restrict__ tbl) {
    __shared__ float lmean[NS_*SP];
    __shared__ float lvar;
    const int t = threadIdx.x;
    const int b = blockIdx.x / BPB;
    const int blk = blockIdx.x % BPB;
    for (int i = t; i < NS_*NE; i += BLK) {
        const int s = i/NE, e = i%NE;
        lmean[s*SP+e] = tbl[T_MEAN + (b*NS_+s)*NE + e];
    }
    if (t == 0) lvar = 0.f;
    __syncthreads();
    const float* ebase = emb + (size_t)b*(NE*NHW);
    const int* lbase = lab + b*NHW;
    float acc = 0.f;
    for (int q = blk*BLK + t; q < NHW/4; q += BPB*BLK) {
        const int p = q*4;
        const int4 l4 = *(const int4*)(lbase + p);
        const int o0 = l4.x*SP, o1 = l4.y*SP, o2 = l4.z*SP, o3 = l4.w*SP;
        float d0=0.f, d1=0.f, d2=0.f, d3=0.f;
        #pragma unroll
        for (int e = 0; e < NE; e++) {
            const float4 v = *(const float4*)(ebase + (size_t)e*NHW + p);
            float df;
            df = v.x - lmean[o0+e]; d0 += df*df;
            df = v.y - lmean[o1+e]; d1 += df*df;
            df = v.z - lmean[o2+e]; d2 += df*df;
            df = v.w - lmean[o3+e]; d3 += df*df;
        }
        if (l4.x > 0) acc += fmaxf(sqrtf(d0) - DELTA_VAR, 0.f);
        if (l4.y > 0) acc += fmaxf(sqrtf(d1) - DELTA_VAR, 0.f);
        if (l4.z > 0) acc += fmaxf(sqrtf(d2) - DELTA_VAR, 0.f);
        if (l4.w > 0) acc += fmaxf(sqrtf(d3) - DELTA_VAR, 0.f);
    }
    const float w = wave_sum(acc);
    if ((t & 63) == 0) atomicAdd(&lvar, w);
    __syncthreads();
    if (t == 0) atomicAdd(&tbl[T_VARP+b], lvar);
}

__global__ void k_final(const float* __restrict__ tbl, float* __restrict__ out) {
    if (threadIdx.x == 0 && blockIdx.x == 0) {
        float tot = 0.f;
        for (int b = 0; b < NB; b++) {
            tot += ALPHA * (tbl[T_VARP+b] / tbl[T_NS+b])
                 + BETA * tbl[T_DIST+b]
                 + GAMMA * tbl[T_REG+b];
        }
        out[0] = tot * (1.f/NB);
    }
}

extern "C" void kernel_launch(void* const* d_in, const int* in_sizes, int n_in,
                              void* d_out, int out_size, void* d_ws, size_t ws_size,
                              hipStream_t stream) {
    const float* emb = (const float*)d_in[0];
    const int* lab = (const int*)d_in[1];
    float* out = (float*)d_out;
    float* ws = (float*)d_ws;

    int nshard = 8;
    if (ws_size < ((size_t)nshard*TABLE + T_TOTAL)*sizeof(float)) nshard = 1;
    float* shards = ws;
    float* tbl = ws + (size_t)nshard*TABLE;
    const size_t zbytes = ((size_t)nshard*TABLE + T_TOTAL)*sizeof(float);

    hipMemsetAsync(d_ws, 0, zbytes, stream);
    k_hist<<<GRID_BIG, BLK, 0, stream>>>(emb, lab, shards, nshard);
    k_reduce<<<(TABLE + 255)/256, 256, 0, stream>>>(shards, tbl, nshard);
    k_stats<<<NB, 64, 0, stream>>>(tbl);
    k_var<<<GRID_BIG, BLK, 0, stream>>>(emb, lab, tbl);
    k_final<<<1, 64, 0, stream>>>(tbl, out);
}

// Round 2
// 130.329 us; speedup vs baseline: 1.0539x; 1.0539x over previous
//
#include <hip/hip_runtime.h>

#define NB 4
#define NE 16
#define NH 512
#define NW 512
#define NHW (NH*NW)
#define NINST 32
#define NS_ (NINST+1)          // 33 segments per batch
#define SP 17                  // padded stride within a histogram copy
#define NCPY 16                // sub-histogram copies per block
#define HST (NS_*SP)           // 561 floats per copy
#define DELTA_VAR 0.5f
#define DELTA_DIST 1.5f
#define ALPHA 1.0f
#define BETA 1.0f
#define GAMMA 0.001f

// k_hist geometry: 256 blocks x 512 threads, 2 grid-stride iters/thread
#define GRID_H 256
#define BLK_H 512
#define BPB_H (GRID_H/NB)      // 64 blocks per batch
// k_var geometry: 512 blocks x 256 threads, 2 iters/thread
#define GRID_V 512
#define BLK_V 256
#define BPB_V (GRID_V/NB)      // 128 blocks per batch

// per-shard table: sums[NB*NS_*NE] then counts[NB*NS_]
#define SUMSZ (NB*NS_*NE)      // 2112
#define CNTSZ (NB*NS_)         // 132
#define TABLE (SUMSZ + CNTSZ)  // 2244
#define NSHARD 8
// final tbl layout (floats):
#define T_MEAN 0               // [NB*NS_*NE) means
#define T_VARP (NB*NS_*NE)     // [.. +NB) var hinge-sum per batch
#define T_DIST (T_VARP+NB)
#define T_REG  (T_DIST+NB)
#define T_NS   (T_REG+NB)
#define T_TOTAL (T_NS+NB)

__device__ __forceinline__ float wave_sum(float v) {
    #pragma unroll
    for (int o = 32; o > 0; o >>= 1) v += __shfl_down(v, o, 64);
    return v;
}

__global__ __launch_bounds__(BLK_H) void k_hist(const float* __restrict__ emb,
        const int* __restrict__ lab, float* __restrict__ shards) {
    // 16 copies of (33x17 sums) followed by 16 copies of 33 counts
    __shared__ __align__(16) float hs[NCPY*HST + NCPY*NS_];   // 9504 floats = 38 KB
    float* hc = hs + NCPY*HST;
    const int t = threadIdx.x;
    const int b = blockIdx.x / BPB_H;
    const int blk = blockIdx.x % BPB_H;
    const int cp = t & (NCPY-1);

    // zero LDS (float4)
    float4* z4 = (float4*)hs;
    for (int i = t; i < (NCPY*HST + NCPY*NS_)/4; i += BLK_H)
        z4[i] = make_float4(0.f, 0.f, 0.f, 0.f);
    __syncthreads();

    const float* ebase = emb + (size_t)b*(NE*NHW);
    const int* lbase = lab + b*NHW;
    float* hbase = hs + cp*HST;
    float* cbase = hc + cp*NS_;

    for (int q = blk*BLK_H + t; q < NHW/4; q += BPB_H*BLK_H) {
        const int p = q*4;
        const int4 l4 = *(const int4*)(lbase + p);
        float* h0 = hbase + l4.x*SP;
        float* h1 = hbase + l4.y*SP;
        float* h2 = hbase + l4.z*SP;
        float* h3 = hbase + l4.w*SP;
        atomicAdd(&cbase[l4.x], 1.f);
        atomicAdd(&cbase[l4.y], 1.f);
        atomicAdd(&cbase[l4.z], 1.f);
        atomicAdd(&cbase[l4.w], 1.f);
        #pragma unroll
        for (int e = 0; e < NE; e++) {
            const float4 v = *(const float4*)(ebase + (size_t)e*NHW + p);
            atomicAdd(&h0[e], v.x);
            atomicAdd(&h1[e], v.y);
            atomicAdd(&h2[e], v.z);
            atomicAdd(&h3[e], v.w);
        }
    }
    __syncthreads();

    // flush: reduce 16 copies, one global atomic per (s,e)
    float* sh = shards + (size_t)(blk % NSHARD)*TABLE;
    for (int i = t; i < NS_*NE; i += BLK_H) {
        const int s = i/NE, e = i%NE;
        float v = 0.f;
        #pragma unroll
        for (int c = 0; c < NCPY; c++) v += hs[c*HST + s*SP + e];
        atomicAdd(&sh[(b*NS_+s)*NE + e], v);
    }
    for (int i = t; i < NS_; i += BLK_H) {
        float v = 0.f;
        #pragma unroll
        for (int c = 0; c < NCPY; c++) v += hc[c*NS_ + i];
        atomicAdd(&sh[SUMSZ + b*NS_ + i], v);
    }
}

// folds shard reduction + means + dist/reg stats
__global__ void k_stats(const float* __restrict__ shards, float* __restrict__ tbl) {
    const int b = blockIdx.x;
    const int lane = threadIdx.x;
    __shared__ float lcnt[NS_];
    __shared__ float lmean[NINST*SP];
    __shared__ int lpres[NINST];
    if (lane < NS_) {
        float c = 0.f;
        #pragma unroll
        for (int sh = 0; sh < NSHARD; sh++) c += shards[(size_t)sh*TABLE + SUMSZ + b*NS_ + lane];
        lcnt[lane] = c;
    }
    __syncthreads();
    for (int idx = lane; idx < NS_*NE; idx += 64) {
        const int s = idx/NE, e = idx%NE;
        float v = 0.f;
        #pragma unroll
        for (int sh = 0; sh < NSHARD; sh++) v += shards[(size_t)sh*TABLE + (b*NS_+s)*NE + e];
        const float m = v / fmaxf(lcnt[s], 1.f);
        tbl[T_MEAN + (b*NS_+s)*NE + e] = m;
        if (s >= 1) lmean[(s-1)*SP + e] = m;
    }
    if (lane < NINST) lpres[lane] = (lcnt[1+lane] > 0.f) ? 1 : 0;
    __syncthreads();
    const int n = __popcll(__ballot(lane < NINST && lpres[lane]));
    float dsum = 0.f;
    for (int idx = lane; idx < NINST*NINST; idx += 64) {
        const int i = idx >> 5, j = idx & 31;
        if (i < j && lpres[i] && lpres[j]) {
            float d2 = 0.f;
            #pragma unroll
            for (int e = 0; e < NE; e++) {
                const float df = lmean[i*SP+e] - lmean[j*SP+e];
                d2 += df*df;
            }
            dsum += fmaxf(2.f*DELTA_DIST - sqrtf(d2), 0.f);
        }
    }
    dsum = wave_sum(dsum);
    float rsum = 0.f;
    if (lane < NINST && lpres[lane]) {
        float s2 = 0.f;
        #pragma unroll
        for (int e = 0; e < NE; e++) { const float m = lmean[lane*SP+e]; s2 += m*m; }
        rsum = sqrtf(s2);
    }
    rsum = wave_sum(rsum);
    if (lane == 0) {
        const float nf = (float)n;
        const float nsafe = fmaxf(nf, 1.f);
        tbl[T_DIST+b] = (n > 1) ? dsum / fmaxf(nf*(nf-1.f)*0.5f, 1.f) : 0.f;
        tbl[T_REG+b] = rsum / nsafe;
        tbl[T_NS+b] = nsafe;
    }
}

__global__ __launch_bounds__(BLK_V) void k_var(const float* __restrict__ emb,
        const int* __restrict__ lab, float* __restrict__ tbl) {
    __shared__ float lmean[NS_*SP];
    __shared__ float lvar;
    const int t = threadIdx.x;
    const int b = blockIdx.x / BPB_V;
    const int blk = blockIdx.x % BPB_V;
    for (int i = t; i < NS_*NE; i += BLK_V) {
        const int s = i/NE, e = i%NE;
        lmean[s*SP+e] = tbl[T_MEAN + (b*NS_+s)*NE + e];
    }
    if (t == 0) lvar = 0.f;
    __syncthreads();
    const float* ebase = emb + (size_t)b*(NE*NHW);
    const int* lbase = lab + b*NHW;
    float acc = 0.f;
    for (int q = blk*BLK_V + t; q < NHW/4; q += BPB_V*BLK_V) {
        const int p = q*4;
        const int4 l4 = *(const int4*)(lbase + p);
        const int o0 = l4.x*SP, o1 = l4.y*SP, o2 = l4.z*SP, o3 = l4.w*SP;
        float d0=0.f, d1=0.f, d2=0.f, d3=0.f;
        #pragma unroll
        for (int e = 0; e < NE; e++) {
            const float4 v = *(const float4*)(ebase + (size_t)e*NHW + p);
            float df;
            df = v.x - lmean[o0+e]; d0 += df*df;
            df = v.y - lmean[o1+e]; d1 += df*df;
            df = v.z - lmean[o2+e]; d2 += df*df;
            df = v.w - lmean[o3+e]; d3 += df*df;
        }
        if (l4.x > 0) acc += fmaxf(sqrtf(d0) - DELTA_VAR, 0.f);
        if (l4.y > 0) acc += fmaxf(sqrtf(d1) - DELTA_VAR, 0.f);
        if (l4.z > 0) acc += fmaxf(sqrtf(d2) - DELTA_VAR, 0.f);
        if (l4.w > 0) acc += fmaxf(sqrtf(d3) - DELTA_VAR, 0.f);
    }
    const float w = wave_sum(acc);
    if ((t & 63) == 0) atomicAdd(&lvar, w);
    __syncthreads();
    if (t == 0) atomicAdd(&tbl[T_VARP+b], lvar);
}

__global__ void k_final(const float* __restrict__ tbl, float* __restrict__ out) {
    if (threadIdx.x == 0 && blockIdx.x == 0) {
        float tot = 0.f;
        for (int b = 0; b < NB; b++) {
            tot += ALPHA * (tbl[T_VARP+b] / tbl[T_NS+b])
                 + BETA * tbl[T_DIST+b]
                 + GAMMA * tbl[T_REG+b];
        }
        out[0] = tot * (1.f/NB);
    }
}

extern "C" void kernel_launch(void* const* d_in, const int* in_sizes, int n_in,
                              void* d_out, int out_size, void* d_ws, size_t ws_size,
                              hipStream_t stream) {
    const float* emb = (const float*)d_in[0];
    const int* lab = (const int*)d_in[1];
    float* out = (float*)d_out;
    float* ws = (float*)d_ws;

    float* shards = ws;
    float* tbl = ws + (size_t)NSHARD*TABLE;
    const size_t zbytes = ((size_t)NSHARD*TABLE + T_TOTAL)*sizeof(float);

    hipMemsetAsync(d_ws, 0, zbytes, stream);
    k_hist<<<GRID_H, BLK_H, 0, stream>>>(emb, lab, shards);
    k_stats<<<NB, 64, 0, stream>>>(shards, tbl);
    k_var<<<GRID_V, BLK_V, 0, stream>>>(emb, lab, tbl);
    k_final<<<1, 64, 0, stream>>>(tbl, out);
}

// Round 3
// 61.897 us; speedup vs baseline: 2.2190x; 2.1056x over previous
//
#include <hip/hip_runtime.h>

#define NB 4
#define NE 16
#define NHW (512*512)
#define NINST 32
#define SP 17
#define DELTA_VAR 0.5f
#define DELTA_DIST 1.5f
#define ALPHA 1.0f
#define BETA 1.0f
#define GAMMA 0.001f

typedef __attribute__((ext_vector_type(8))) short short8;
typedef __attribute__((ext_vector_type(4))) float f32x4;

// tbl layout (floats in d_ws)
#define T_SUM 0                       // [NB][32][16]  label-1 major
#define T_CNT (NB*NINST*NE)           // 2048: [NB][32]
#define T_MEAN (T_CNT + NB*NINST)     // 2176: [NB][33][16] (seg 0 = zeros)
#define T_VARP (T_MEAN + NB*33*NE)    // 4288
#define T_DIST (T_VARP+NB)
#define T_REG  (T_DIST+NB)
#define T_NS   (T_REG+NB)
#define T_TOTAL (T_NS+NB)             // 4304 floats

// k_hist: 1024 blocks x 256 thr (4 waves); wave owns 256 px (4 iters x 64 px)
#define GRID_H 1024
#define BLK_H 256
#define BPB_H (GRID_H/NB)             // 256 blocks/batch
#define PXB 1024                      // px per block
#define PXW 256                       // px per wave
#define ITERS_H 4
// k_var: 1024 blocks x 256 thr, 4 px/thread
#define GRID_V 1024
#define BLK_V 256
#define BPB_V (GRID_V/NB)

__device__ __forceinline__ unsigned f2bf(float x) {
    unsigned u = __builtin_bit_cast(unsigned, x);
    return (u + 0x7FFFu + ((u >> 16) & 1u)) >> 16;   // RNE bf16 bits in [15:0]
}

__device__ __forceinline__ float wave_sum(float v) {
    #pragma unroll
    for (int o = 32; o > 0; o >>= 1) v += __shfl_down(v, o, 64);
    return v;
}

union PK { unsigned u[4]; short8 s; };

__global__ __launch_bounds__(BLK_H) void k_hist(const float* __restrict__ emb,
        const int* __restrict__ lab, float* __restrict__ tbl) {
    __shared__ float red[4][2*NE][SP];    // [wave][seg(=label-1)][ch], padded
    __shared__ float redc[4][2*NE];
    const int t = threadIdx.x;
    const int lane = t & 63;
    const int wv = t >> 6;
    const int colg = lane >> 4;           // k-octet group 0..3
    const int cm = lane & 15;             // A: seg-within-half ; B: channel
    const int b = blockIdx.x / BPB_H;
    const int blk = blockIdx.x % BPB_H;

    const float* ebase = emb + (size_t)b*(NE*NHW) + (size_t)cm*NHW;
    const int* lbase = lab + (size_t)b*NHW;

    f32x4 acc_s0 = {0.f,0.f,0.f,0.f}, acc_s1 = {0.f,0.f,0.f,0.f};
    f32x4 acc_c0 = {0.f,0.f,0.f,0.f}, acc_c1 = {0.f,0.f,0.f,0.f};
    PK ones; ones.u[0]=ones.u[1]=ones.u[2]=ones.u[3]=0x3F803F80u;

    const int base = blk*PXB + wv*PXW;
    for (int it = 0; it < ITERS_H; ++it) {
        #pragma unroll
        for (int u2 = 0; u2 < 2; ++u2) {
            const int ko = base + it*64 + u2*32 + colg*8;
            const float4 v0 = *(const float4*)(ebase + ko);
            const float4 v1 = *(const float4*)(ebase + ko + 4);
            const int4 L0 = *(const int4*)(lbase + ko);
            const int4 L1 = *(const int4*)(lbase + ko + 4);
            PK bf;
            bf.u[0] = f2bf(v0.x) | (f2bf(v0.y) << 16);
            bf.u[1] = f2bf(v0.z) | (f2bf(v0.w) << 16);
            bf.u[2] = f2bf(v1.x) | (f2bf(v1.y) << 16);
            bf.u[3] = f2bf(v1.z) | (f2bf(v1.w) << 16);
            const int la[8] = {L0.x,L0.y,L0.z,L0.w,L1.x,L1.y,L1.z,L1.w};
            PK a0, a1;
            #pragma unroll
            for (int p = 0; p < 4; ++p) {
                const unsigned lo0 = (la[2*p]   == cm+1 ) ? 0x3F80u : 0u;
                const unsigned hi0 = (la[2*p+1] == cm+1 ) ? 0x3F80u : 0u;
                const unsigned lo1 = (la[2*p]   == cm+17) ? 0x3F80u : 0u;
                const unsigned hi1 = (la[2*p+1] == cm+17) ? 0x3F80u : 0u;
                a0.u[p] = lo0 | (hi0 << 16);
                a1.u[p] = lo1 | (hi1 << 16);
            }
            acc_s0 = __builtin_amdgcn_mfma_f32_16x16x32_bf16(a0.s, bf.s,  acc_s0, 0,0,0);
            acc_s1 = __builtin_amdgcn_mfma_f32_16x16x32_bf16(a1.s, bf.s,  acc_s1, 0,0,0);
            acc_c0 = __builtin_amdgcn_mfma_f32_16x16x32_bf16(a0.s, ones.s, acc_c0, 0,0,0);
            acc_c1 = __builtin_amdgcn_mfma_f32_16x16x32_bf16(a1.s, ones.s, acc_c1, 0,0,0);
        }
    }
    // D layout (m89-verified): col = lane&15 (channel), row = colg*4 + r (seg in half)
    #pragma unroll
    for (int r = 0; r < 4; ++r) {
        red[wv][colg*4 + r][cm]      = acc_s0[r];
        red[wv][16 + colg*4 + r][cm] = acc_s1[r];
    }
    if (cm == 0) {
        #pragma unroll
        for (int r = 0; r < 4; ++r) {
            redc[wv][colg*4 + r]      = acc_c0[r];
            redc[wv][16 + colg*4 + r] = acc_c1[r];
        }
    }
    __syncthreads();
    for (int i = t; i < NINST*NE; i += BLK_H) {
        const int s = i >> 4, e = i & 15;
        const float v = red[0][s][e] + red[1][s][e] + red[2][s][e] + red[3][s][e];
        atomicAdd(&tbl[T_SUM + b*NINST*NE + i], v);
    }
    if (t < NINST) {
        const float v = redc[0][t] + redc[1][t] + redc[2][t] + redc[3][t];
        atomicAdd(&tbl[T_CNT + b*NINST + t], v);
    }
}

__global__ void k_stats(float* __restrict__ tbl) {
    const int b = blockIdx.x;
    const int lane = threadIdx.x;
    __shared__ float lcnt[NINST];
    __shared__ float lmean[NINST*SP];
    __shared__ int lpres[NINST];
    if (lane < NINST) {
        const float c = tbl[T_CNT + b*NINST + lane];
        lcnt[lane] = c;
        lpres[lane] = (c > 0.f) ? 1 : 0;
    }
    __syncthreads();
    for (int i = lane; i < NINST*NE; i += 64) {
        const int s = i >> 4, e = i & 15;
        const float m = tbl[T_SUM + b*NINST*NE + i] / fmaxf(lcnt[s], 1.f);
        lmean[s*SP + e] = m;
        tbl[T_MEAN + b*33*NE + (s+1)*NE + e] = m;   // label s+1
    }
    if (lane < NE) tbl[T_MEAN + b*33*NE + lane] = 0.f;  // label 0 slot
    __syncthreads();
    const int n = __popcll(__ballot((lane < NINST) ? (lpres[lane] != 0) : false));
    float dsum = 0.f;
    for (int idx = lane; idx < NINST*NINST; idx += 64) {
        const int i = idx >> 5, j = idx & 31;
        if (i < j && lpres[i] && lpres[j]) {
            float d2 = 0.f;
            #pragma unroll
            for (int e = 0; e < NE; e++) {
                const float df = lmean[i*SP+e] - lmean[j*SP+e];
                d2 += df*df;
            }
            dsum += fmaxf(2.f*DELTA_DIST - sqrtf(d2), 0.f);
        }
    }
    dsum = wave_sum(dsum);
    float rsum = 0.f;
    if (lane < NINST && lpres[lane]) {
        float s2 = 0.f;
        #pragma unroll
        for (int e = 0; e < NE; e++) { const float m = lmean[lane*SP+e]; s2 += m*m; }
        rsum = sqrtf(s2);
    }
    rsum = wave_sum(rsum);
    if (lane == 0) {
        const float nf = (float)n;
        const float nsafe = fmaxf(nf, 1.f);
        tbl[T_DIST+b] = (n > 1) ? dsum / fmaxf(nf*(nf-1.f)*0.5f, 1.f) : 0.f;
        tbl[T_REG+b] = rsum / nsafe;
        tbl[T_NS+b] = nsafe;
    }
}

__global__ __launch_bounds__(BLK_V) void k_var(const float* __restrict__ emb,
        const int* __restrict__ lab, float* __restrict__ tbl) {
    __shared__ float lmean[33*SP];
    __shared__ float lvar;
    const int t = threadIdx.x;
    const int b = blockIdx.x / BPB_V;
    const int blk = blockIdx.x % BPB_V;
    for (int i = t; i < 33*NE; i += BLK_V) {
        const int s = i >> 4, e = i & 15;
        lmean[s*SP+e] = tbl[T_MEAN + b*33*NE + i];
        (void)s; (void)e;
    }
    // fix indexing: i = s*16+e
    __syncthreads();
    if (t == 0) lvar = 0.f;
    __syncthreads();
    const float* ebase = emb + (size_t)b*(NE*NHW);
    const int* lbase = lab + (size_t)b*NHW;
    float acc = 0.f;
    for (int q = blk*BLK_V + t; q < NHW/4; q += BPB_V*BLK_V) {
        const int p = q*4;
        const int4 l4 = *(const int4*)(lbase + p);
        const int o0 = l4.x*SP, o1 = l4.y*SP, o2 = l4.z*SP, o3 = l4.w*SP;
        float d0=0.f, d1=0.f, d2=0.f, d3=0.f;
        #pragma unroll
        for (int e = 0; e < NE; e++) {
            const float4 v = *(const float4*)(ebase + (size_t)e*NHW + p);
            float df;
            df = v.x - lmean[o0+e]; d0 += df*df;
            df = v.y - lmean[o1+e]; d1 += df*df;
            df = v.z - lmean[o2+e]; d2 += df*df;
            df = v.w - lmean[o3+e]; d3 += df*df;
        }
        if (l4.x > 0) acc += fmaxf(sqrtf(d0) - DELTA_VAR, 0.f);
        if (l4.y > 0) acc += fmaxf(sqrtf(d1) - DELTA_VAR, 0.f);
        if (l4.z > 0) acc += fmaxf(sqrtf(d2) - DELTA_VAR, 0.f);
        if (l4.w > 0) acc += fmaxf(sqrtf(d3) - DELTA_VAR, 0.f);
    }
    const float w = wave_sum(acc);
    if ((t & 63) == 0) atomicAdd(&lvar, w);
    __syncthreads();
    if (t == 0) atomicAdd(&tbl[T_VARP+b], lvar);
}

__global__ void k_final(const float* __restrict__ tbl, float* __restrict__ out) {
    if (threadIdx.x == 0 && blockIdx.x == 0) {
        float tot = 0.f;
        for (int b = 0; b < NB; b++) {
            tot += ALPHA * (tbl[T_VARP+b] / tbl[T_NS+b])
                 + BETA * tbl[T_DIST+b]
                 + GAMMA * tbl[T_REG+b];
        }
        out[0] = tot * (1.f/NB);
    }
}

extern "C" void kernel_launch(void* const* d_in, const int* in_sizes, int n_in,
                              void* d_out, int out_size, void* d_ws, size_t ws_size,
                              hipStream_t stream) {
    const float* emb = (const float*)d_in[0];
    const int* lab = (const int*)d_in[1];
    float* out = (float*)d_out;
    float* tbl = (float*)d_ws;

    hipMemsetAsync(d_ws, 0, (size_t)T_TOTAL*sizeof(float), stream);
    k_hist<<<GRID_H, BLK_H, 0, stream>>>(emb, lab, tbl);
    k_stats<<<NB, 64, 0, stream>>>(tbl);
    k_var<<<GRID_V, BLK_V, 0, stream>>>(emb, lab, tbl);
    k_final<<<1, 64, 0, stream>>>(tbl, out);
}

// Round 4
// 53.463 us; speedup vs baseline: 2.5690x; 1.1578x over previous
//
#include <hip/hip_runtime.h>

#define NB 4
#define NE 16
#define NHW (512*512)
#define NINST 32
#define DELTA_VAR 0.5f
#define DELTA_DIST 1.5f
#define ALPHA 1.0f
#define BETA 1.0f
#define GAMMA 0.001f

typedef __attribute__((ext_vector_type(8))) short short8;
typedef __attribute__((ext_vector_type(4))) float f32x4;

// ---- workspace layout (floats), all slots written before read each call ----
#define PH_STRIDE 544                 // per-block partial: [32][16] sums + [32] counts
#define GRID_H 256
#define P_HIST 0                      // [GRID_H][PH_STRIDE]
#define T_MEAN (GRID_H*PH_STRIDE)     // [33][16] per batch? -> [NB? no: per batch stored batch-major below]
// NOTE: means stored per batch: [NB][33*16]? k_stats block b writes its own; k_var reads by b.
#define T_MEAN_SZ (33*16)
#define T_DIST (T_MEAN + NB*T_MEAN_SZ)
#define T_REG  (T_DIST + NB)
#define T_NS   (T_REG + NB)
#define V_PART (T_NS + NB)            // [1024]
// total ~ 141,436 floats ≈ 566 KB

// k_hist: 256 blocks x 512 thr (8 waves); wave owns 512 px = 16 chunks of 32 px
#define BLK_H 512
#define BPB_H (GRID_H/NB)             // 64 blocks per batch
#define PXB_H 4096
#define PXW_H 512
#define CHUNKS_H 16
// k_var: 1024 blocks x 256 thr, 4 px/thread
#define GRID_V 1024
#define BLK_V 256
#define BPB_V (GRID_V/NB)             // 256

#define LMREP 4                       // mean replicas in k_var LDS
#define LMSTR 668                     // 33*20 + 8 pad (16B-aligned, bank-shifted)

__device__ __forceinline__ unsigned f2bf(float x) {
    unsigned u = __builtin_bit_cast(unsigned, x);
    return (u + 0x7FFFu + ((u >> 16) & 1u)) >> 16;   // RNE bf16
}

__device__ __forceinline__ float wave_sum(float v) {
    #pragma unroll
    for (int o = 32; o > 0; o >>= 1) v += __shfl_down(v, o, 64);
    return v;
}

union PK { unsigned u[4]; short8 s; };

__global__ __launch_bounds__(BLK_H) void k_hist(const float* __restrict__ emb,
        const int* __restrict__ lab, float* __restrict__ ws) {
    __shared__ float red[8][2*NE][17];
    __shared__ float redc[8][2*NE];
    const int t = threadIdx.x;
    const int lane = t & 63;
    const int wv = t >> 6;
    const int colg = lane >> 4;
    const int cm = lane & 15;
    const int b = blockIdx.x / BPB_H;
    const int blk = blockIdx.x % BPB_H;

    const float* ebase = emb + (size_t)b*(NE*NHW) + (size_t)cm*NHW;
    const int* lbase = lab + (size_t)b*NHW;

    f32x4 acc_s0 = {0.f,0.f,0.f,0.f}, acc_s1 = {0.f,0.f,0.f,0.f};
    f32x4 acc_c0 = {0.f,0.f,0.f,0.f}, acc_c1 = {0.f,0.f,0.f,0.f};
    PK ones; ones.u[0]=ones.u[1]=ones.u[2]=ones.u[3]=0x3F803F80u;

    const int base = blk*PXB_H + wv*PXW_H;
    #pragma unroll 4
    for (int it = 0; it < CHUNKS_H; ++it) {
        const int ko = base + it*32 + colg*8;
        const float4 v0 = *(const float4*)(ebase + ko);
        const float4 v1 = *(const float4*)(ebase + ko + 4);
        const int4 L0 = *(const int4*)(lbase + ko);
        const int4 L1 = *(const int4*)(lbase + ko + 4);
        PK bf;
        bf.u[0] = f2bf(v0.x) | (f2bf(v0.y) << 16);
        bf.u[1] = f2bf(v0.z) | (f2bf(v0.w) << 16);
        bf.u[2] = f2bf(v1.x) | (f2bf(v1.y) << 16);
        bf.u[3] = f2bf(v1.z) | (f2bf(v1.w) << 16);
        const int la[8] = {L0.x,L0.y,L0.z,L0.w,L1.x,L1.y,L1.z,L1.w};
        PK a0, a1;
        #pragma unroll
        for (int p = 0; p < 4; ++p) {
            const unsigned lo0 = (la[2*p]   == cm+1 ) ? 0x3F80u : 0u;
            const unsigned hi0 = (la[2*p+1] == cm+1 ) ? 0x3F80u : 0u;
            const unsigned lo1 = (la[2*p]   == cm+17) ? 0x3F80u : 0u;
            const unsigned hi1 = (la[2*p+1] == cm+17) ? 0x3F80u : 0u;
            a0.u[p] = lo0 | (hi0 << 16);
            a1.u[p] = lo1 | (hi1 << 16);
        }
        acc_s0 = __builtin_amdgcn_mfma_f32_16x16x32_bf16(a0.s, bf.s,   acc_s0, 0,0,0);
        acc_s1 = __builtin_amdgcn_mfma_f32_16x16x32_bf16(a1.s, bf.s,   acc_s1, 0,0,0);
        acc_c0 = __builtin_amdgcn_mfma_f32_16x16x32_bf16(a0.s, ones.s, acc_c0, 0,0,0);
        acc_c1 = __builtin_amdgcn_mfma_f32_16x16x32_bf16(a1.s, ones.s, acc_c1, 0,0,0);
    }
    // D layout: col = lane&15 (channel), row = colg*4 + r (seg within half)
    #pragma unroll
    for (int r = 0; r < 4; ++r) {
        red[wv][colg*4 + r][cm]      = acc_s0[r];
        red[wv][16 + colg*4 + r][cm] = acc_s1[r];
    }
    if (cm == 0) {
        #pragma unroll
        for (int r = 0; r < 4; ++r) {
            redc[wv][colg*4 + r]      = acc_c0[r];
            redc[wv][16 + colg*4 + r] = acc_c1[r];
        }
    }
    __syncthreads();
    float* dst = ws + P_HIST + (size_t)blockIdx.x*PH_STRIDE;
    for (int i = t; i < PH_STRIDE; i += BLK_H) {
        float v;
        if (i < 512) {
            const int s = i >> 4, e = i & 15;
            v = red[0][s][e]+red[1][s][e]+red[2][s][e]+red[3][s][e]
              + red[4][s][e]+red[5][s][e]+red[6][s][e]+red[7][s][e];
        } else {
            const int s = i - 512;
            v = redc[0][s]+redc[1][s]+redc[2][s]+redc[3][s]
              + redc[4][s]+redc[5][s]+redc[6][s]+redc[7][s];
        }
        dst[i] = v;
    }
}

__global__ void k_stats(float* __restrict__ ws) {
    const int b = blockIdx.x;
    const int t = threadIdx.x;
    __shared__ float lred[PH_STRIDE];
    __shared__ float lmean[NINST*17];
    __shared__ float lcnt[NINST];
    __shared__ int lpres[NINST];
    const float* ph = ws + P_HIST + (size_t)(b*BPB_H)*PH_STRIDE;
    for (int i = t; i < PH_STRIDE; i += 256) {
        float s = 0.f;
        #pragma unroll 8
        for (int k = 0; k < BPB_H; k++) s += ph[(size_t)k*PH_STRIDE + i];
        lred[i] = s;
    }
    __syncthreads();
    if (t < NINST) {
        const float c = lred[512 + t];
        lcnt[t] = c;
        lpres[t] = (c > 0.f) ? 1 : 0;
    }
    __syncthreads();
    for (int i = t; i < 512; i += 256) {
        const int s = i >> 4, e = i & 15;
        lmean[s*17 + e] = lred[i] / fmaxf(lcnt[s], 1.f);
    }
    __syncthreads();
    // global means [33][16], label 0 = zeros
    for (int i = t; i < 33*NE; i += 256) {
        const int l = i >> 4, e = i & 15;
        ws[T_MEAN + b*T_MEAN_SZ + i] = (l == 0) ? 0.f : lmean[(l-1)*17 + e];
    }
    if (t < 64) {
        const int lane = t;
        const int n = __popcll(__ballot((lane < NINST) ? (lpres[lane] != 0) : false));
        float dsum = 0.f;
        for (int idx = lane; idx < NINST*NINST; idx += 64) {
            const int i = idx >> 5, j = idx & 31;
            if (i < j && lpres[i] && lpres[j]) {
                float d2 = 0.f;
                #pragma unroll
                for (int e = 0; e < NE; e++) {
                    const float df = lmean[i*17+e] - lmean[j*17+e];
                    d2 += df*df;
                }
                dsum += fmaxf(2.f*DELTA_DIST - sqrtf(d2), 0.f);
            }
        }
        dsum = wave_sum(dsum);
        float rsum = 0.f;
        if (lane < NINST && lpres[lane]) {
            float s2 = 0.f;
            #pragma unroll
            for (int e = 0; e < NE; e++) { const float m = lmean[lane*17+e]; s2 += m*m; }
            rsum = sqrtf(s2);
        }
        rsum = wave_sum(rsum);
        if (lane == 0) {
            const float nf = (float)n;
            const float nsafe = fmaxf(nf, 1.f);
            ws[T_DIST+b] = (n > 1) ? dsum / fmaxf(nf*(nf-1.f)*0.5f, 1.f) : 0.f;
            ws[T_REG+b] = rsum / nsafe;
            ws[T_NS+b] = nsafe;
        }
    }
}

__global__ __launch_bounds__(BLK_V) void k_var(const float* __restrict__ emb,
        const int* __restrict__ lab, float* __restrict__ ws) {
    __shared__ __align__(16) float lm[LMREP*LMSTR];
    __shared__ float wred[4];
    const int t = threadIdx.x;
    const int b = blockIdx.x >> 8;
    const int blk = blockIdx.x & 255;
    // fill 4 replicated mean tables, [33][20] each (cols 16..19 unused)
    for (int c4 = 0; c4 < LMREP; ++c4) {
        for (int i = t; i < 33*20; i += BLK_V) {
            const int l = i / 20, e = i % 20;
            if (e < 16) lm[c4*LMSTR + i] = ws[T_MEAN + b*T_MEAN_SZ + l*16 + e];
        }
    }
    __syncthreads();
    const float* lmc = lm + ((t >> 4) & (LMREP-1))*LMSTR;
    const float* ebase = emb + (size_t)b*(NE*NHW);
    const int* lbase = lab + (size_t)b*NHW;

    const int p = (blk*BLK_V + t)*4;
    const int4 l4 = *(const int4*)(lbase + p);
    float4 m0[4], m1[4], m2[4], m3[4];
    {
        const float4* q0 = (const float4*)(lmc + l4.x*20);
        const float4* q1 = (const float4*)(lmc + l4.y*20);
        const float4* q2 = (const float4*)(lmc + l4.z*20);
        const float4* q3 = (const float4*)(lmc + l4.w*20);
        #pragma unroll
        for (int c = 0; c < 4; ++c) { m0[c]=q0[c]; m1[c]=q1[c]; m2[c]=q2[c]; m3[c]=q3[c]; }
    }
    float d0=0.f, d1=0.f, d2=0.f, d3=0.f;
    #pragma unroll
    for (int e = 0; e < NE; e++) {
        const float4 v = *(const float4*)(ebase + (size_t)e*NHW + p);
        float df;
        df = v.x - ((const float*)&m0[e>>2])[e&3]; d0 += df*df;
        df = v.y - ((const float*)&m1[e>>2])[e&3]; d1 += df*df;
        df = v.z - ((const float*)&m2[e>>2])[e&3]; d2 += df*df;
        df = v.w - ((const float*)&m3[e>>2])[e&3]; d3 += df*df;
    }
    float acc = 0.f;
    if (l4.x > 0) acc += fmaxf(sqrtf(d0) - DELTA_VAR, 0.f);
    if (l4.y > 0) acc += fmaxf(sqrtf(d1) - DELTA_VAR, 0.f);
    if (l4.z > 0) acc += fmaxf(sqrtf(d2) - DELTA_VAR, 0.f);
    if (l4.w > 0) acc += fmaxf(sqrtf(d3) - DELTA_VAR, 0.f);

    const float wsum = wave_sum(acc);
    if ((t & 63) == 0) wred[t >> 6] = wsum;
    __syncthreads();
    if (t == 0) ws[V_PART + blockIdx.x] = wred[0]+wred[1]+wred[2]+wred[3];
}

__global__ void k_final(const float* __restrict__ ws, float* __restrict__ out) {
    const int t = threadIdx.x;              // 256 thr; wave w <-> batch w
    __shared__ float vb[4];
    float s = 0.f;
    #pragma unroll
    for (int k = 0; k < 4; ++k) s += ws[V_PART + t*4 + k];
    s = wave_sum(s);
    if ((t & 63) == 0) vb[t >> 6] = s;
    __syncthreads();
    if (t == 0) {
        float tot = 0.f;
        for (int b = 0; b < NB; b++) {
            tot += ALPHA * (vb[b] / ws[T_NS+b])
                 + BETA * ws[T_DIST+b]
                 + GAMMA * ws[T_REG+b];
        }
        out[0] = tot * (1.f/NB);
    }
}

extern "C" void kernel_launch(void* const* d_in, const int* in_sizes, int n_in,
                              void* d_out, int out_size, void* d_ws, size_t ws_size,
                              hipStream_t stream) {
    const float* emb = (const float*)d_in[0];
    const int* lab = (const int*)d_in[1];
    float* out = (float*)d_out;
    float* ws = (float*)d_ws;

    k_hist<<<GRID_H, BLK_H, 0, stream>>>(emb, lab, ws);
    k_stats<<<NB, 256, 0, stream>>>(ws);
    k_var<<<GRID_V, BLK_V, 0, stream>>>(emb, lab, ws);
    k_final<<<1, 256, 0, stream>>>(ws, out);
}